// Round 14
// baseline (96.235 us; speedup 1.0000x reference)
//
#include <hip/hip_runtime.h>
#include <math.h>

#define B_TOT 2048
#define IN_TOT 512
#define OUT_TOT 512
#define COLS 64         // cols per block = lanes
#define ROWS 32         // rows per block (8 waves x 4 rows)
#define M 4             // rows per wave/thread
#define CKQ 16          // quads per chunk (64 k)
#define NCH 8           // chunks (8 x 64 = 512 k)

__global__ __launch_bounds__(512, 2) void morph_kernel(
    const float* __restrict__ x,
    const float* __restrict__ wdil,
    const float* __restrict__ wero,
    float* __restrict__ out)
{
    // [buf][arr][col*64 + phys_quad*4 + e] : 2*2*4096 floats = 64 KB
    __shared__ float w_s[2][2][COLS * CKQ * 4];

    const int tid  = (int)threadIdx.x;
    const int lane = tid & 63;
    const int wv   = __builtin_amdgcn_readfirstlane(tid >> 6);  // 0..7

    const int col0 = (int)blockIdx.x * COLS;
    const int row0 = (int)blockIdx.y * ROWS;

    // ---- staging map: 1024 slots/chunk/array, 512 threads x 2 iters ----
    // slot s: col c = s>>4, phys quad qq = s&15 holds logical quad qq^(c&15)
    // (source-side swizzle; LDS write linear at s*4 floats)
    int soff[2], lws[2];
#pragma unroll
    for (int i = 0; i < 2; ++i) {
        const int s  = i * 512 + tid;            // [0, 1024)
        const int c  = s >> 4;                   // [0, 64)  ✓ in-block col
        const int qq = s & 15;
        soff[i] = (col0 + c) * IN_TOT + ((qq ^ (c & 15)) << 2);  // + ck*64 later
        lws[i]  = s * 4;                                          // [0, 4096)
    }

    // ---- prologue: stage chunk 0 into buf 0 ----
#pragma unroll
    for (int i = 0; i < 2; ++i) {
        *(float4*)&w_s[0][0][lws[i]] = *(const float4*)(wdil + soff[i]);
        *(float4*)&w_s[0][1][lws[i]] = *(const float4*)(wero + soff[i]);
    }
    __syncthreads();

    float dil[M], ero[M];
#pragma unroll
    for (int r = 0; r < M; ++r) { dil[r] = -INFINITY; ero[r] = INFINITY; }

    // wave-uniform x base: whole wave walks the same 4 rows (scalarizable)
    const float* xw = x + (size_t)(row0 + wv * M) * IN_TOT;

    // lane LDS read base (floats): col region + swizzle seed (lane&15)*4
    const int rb = lane * (CKQ * 4) + ((lane & 15) << 2);

#pragma unroll 1
    for (int ck = 0; ck < NCH; ++ck) {
        const int buf = ck & 1;

        float4 sa[2], sb[2];
        if (ck + 1 < NCH) {     // T14: issue next chunk's global loads early
#pragma unroll
            for (int i = 0; i < 2; ++i) {
                sa[i] = *(const float4*)(wdil + soff[i] + (ck + 1) * 64);
                sb[i] = *(const float4*)(wero + soff[i] + (ck + 1) * 64);
            }
        }

        const float* __restrict__ wdp = &w_s[buf][0][0];
        const float* __restrict__ wep = &w_s[buf][1][0];

#pragma unroll
        for (int qq = 0; qq < CKQ; ++qq) {
            const int ro = rb ^ (qq << 2);          // phys = qq ^ (lane&15)
            float4 wd4 = *(const float4*)(wdp + ro);
            float4 we4 = *(const float4*)(wep + ro);

            float4 xv[M];
#pragma unroll
            for (int r = 0; r < M; ++r)             // wave-uniform: 1 line/inst
                xv[r] = *(const float4*)(xw + r * IN_TOT + ck * 64 + qq * 4);

#pragma unroll
            for (int r = 0; r < M; ++r) {
                dil[r] = fmaxf(fmaxf(xv[r].x + wd4.x, xv[r].y + wd4.y), dil[r]);
                dil[r] = fmaxf(fmaxf(xv[r].z + wd4.z, xv[r].w + wd4.w), dil[r]);
                ero[r] = fminf(fminf(xv[r].x - we4.x, xv[r].y - we4.y), ero[r]);
                ero[r] = fminf(fminf(xv[r].z - we4.z, xv[r].w - we4.w), ero[r]);
            }
        }

        if (ck + 1 < NCH) {     // write-late into the other buffer
            const int nb = buf ^ 1;
#pragma unroll
            for (int i = 0; i < 2; ++i) {
                *(float4*)&w_s[nb][0][lws[i]] = sa[i];
                *(float4*)&w_s[nb][1][lws[i]] = sb[i];
            }
        }
        __syncthreads();
    }

    float* op = out + (size_t)(row0 + wv * M) * OUT_TOT + col0 + lane;
#pragma unroll
    for (int r = 0; r < M; ++r)
        op[(size_t)r * OUT_TOT] = dil[r] + ero[r];   // lane=col: coalesced
}

extern "C" void kernel_launch(void* const* d_in, const int* in_sizes, int n_in,
                              void* d_out, int out_size, void* d_ws, size_t ws_size,
                              hipStream_t stream)
{
    const float* x  = (const float*)d_in[0];
    const float* wd = (const float*)d_in[1];
    const float* we = (const float*)d_in[2];
    float* out = (float*)d_out;

    dim3 grid(OUT_TOT / COLS, B_TOT / ROWS);   // (8, 64) = 512 blocks = 2/CU
    dim3 block(512);                           // 8 waves x (4 rows x 64 cols)
    hipLaunchKernelGGL(morph_kernel, grid, block, 0, stream, x, wd, we, out);
}

// Round 15
// 79.796 us; speedup vs baseline: 1.2060x; 1.2060x over previous
//
#include <hip/hip_runtime.h>
#include <math.h>

#define B_TOT 2048
#define IN_TOT 512
#define OUT_TOT 512
#define COLS 64         // cols per block = lanes
#define ROWS 32         // rows per block = 4 row-groups x 8
#define M 8             // rows per wave
#define CKQ 8           // quads per chunk (32 k)
#define NCH 16          // chunks
#define QW 4            // quads per wave per chunk (half of CKQ)

__global__ __launch_bounds__(512, 2) void morph_kernel(
    const float* __restrict__ x,
    const float* __restrict__ wdil,
    const float* __restrict__ wero,
    float* __restrict__ out)
{
    // [buf][arr][col*32 + phys_quad*4 + e] : 2*2*2048 floats = 32 KB
    // reused as the k-half combine buffer at the end.
    __shared__ float w_s[2][2][COLS * CKQ * 4];

    const int tid  = (int)threadIdx.x;
    const int lane = tid & 63;
    const int wv   = __builtin_amdgcn_readfirstlane(tid >> 6);  // 0..7
    const int rg   = wv & 3;        // row-group
    const int half = wv >> 2;       // k-half: quads [half*4, half*4+4) of each chunk

    const int col0 = (int)blockIdx.x * COLS;
    const int row0 = (int)blockIdx.y * ROWS;

    // ---- staging map: 512 slots per array per chunk, 1 slot/thread ----
    // slot s: col c = s>>3, phys quad p = s&7 holds logical quad p^(c&7)
    const int sc = tid >> 3;
    const int sp = tid & 7;
    const int soff = (col0 + sc) * IN_TOT + ((sp ^ (sc & 7)) << 2); // + ck*32
    const int lws  = tid * 4;                                       // linear write

    // ---- prologue: stage chunk 0 into buf 0 ----
    *(float4*)&w_s[0][0][lws] = *(const float4*)(wdil + soff);
    *(float4*)&w_s[0][1][lws] = *(const float4*)(wero + soff);
    __syncthreads();

    float dil[M], ero[M];
#pragma unroll
    for (int r = 0; r < M; ++r) { dil[r] = -INFINITY; ero[r] = INFINITY; }

    // wave-uniform x base: the wave's 8 rows (1 line-touch per load inst)
    const float* xw = x + (size_t)(row0 + rg * M) * IN_TOT;

    // lane LDS read base (floats) + swizzle seed
    const int rb = lane * (CKQ * 4);
    const int lx = lane & 7;

#pragma unroll 1
    for (int ck = 0; ck < NCH; ++ck) {
        const int buf = ck & 1;

        float4 sa, sb;
        if (ck + 1 < NCH) {     // issue next chunk's global loads early (T14)
            sa = *(const float4*)(wdil + soff + (ck + 1) * 32);
            sb = *(const float4*)(wero + soff + (ck + 1) * 32);
        }

        const float* __restrict__ wdp = &w_s[buf][0][0];
        const float* __restrict__ wep = &w_s[buf][1][0];

#pragma unroll
        for (int j = 0; j < QW; ++j) {
            const int qq = half * QW + j;            // this half's quad
            const int ro = rb + (((qq ^ lx) & 7) << 2);
            float4 wd4 = *(const float4*)(wdp + ro);
            float4 we4 = *(const float4*)(wep + ro);

            float4 xv[M];
#pragma unroll
            for (int r = 0; r < M; ++r)              // wave-uniform loads
                xv[r] = *(const float4*)(xw + r * IN_TOT + ck * 32 + qq * 4);

#pragma unroll
            for (int r = 0; r < M; ++r) {
                dil[r] = fmaxf(fmaxf(xv[r].x + wd4.x, xv[r].y + wd4.y), dil[r]);
                dil[r] = fmaxf(fmaxf(xv[r].z + wd4.z, xv[r].w + wd4.w), dil[r]);
                ero[r] = fminf(fminf(xv[r].x - we4.x, xv[r].y - we4.y), ero[r]);
                ero[r] = fminf(fminf(xv[r].z - we4.z, xv[r].w - we4.w), ero[r]);
            }
        }

        if (ck + 1 < NCH) {     // write-late into the other buffer
            const int nb = buf ^ 1;
            *(float4*)&w_s[nb][0][lws] = sa;
            *(float4*)&w_s[nb][1][lws] = sb;
        }
        __syncthreads();
    }

    // ---- combine the two k-halves (exact: max/min associative) ----
    float* pb = &w_s[0][0][0];      // 8192 floats, reuse after last barrier
    if (half == 1) {
#pragma unroll
        for (int r = 0; r < M; ++r) {
            pb[rg * 512 + r * 64 + lane]        = dil[r];  // stride-1: conflict-free
            pb[4096 + rg * 512 + r * 64 + lane] = ero[r];
        }
    }
    __syncthreads();
    if (half == 0) {
        float* op = out + (size_t)(row0 + rg * M) * OUT_TOT + col0 + lane;
#pragma unroll
        for (int r = 0; r < M; ++r) {
            float d = fmaxf(dil[r], pb[rg * 512 + r * 64 + lane]);
            float e = fminf(ero[r], pb[4096 + rg * 512 + r * 64 + lane]);
            op[(size_t)r * OUT_TOT] = d + e;          // lane=col: coalesced
        }
    }
}

extern "C" void kernel_launch(void* const* d_in, const int* in_sizes, int n_in,
                              void* d_out, int out_size, void* d_ws, size_t ws_size,
                              hipStream_t stream)
{
    const float* x  = (const float*)d_in[0];
    const float* wd = (const float*)d_in[1];
    const float* we = (const float*)d_in[2];
    float* out = (float*)d_out;

    dim3 grid(OUT_TOT / COLS, B_TOT / ROWS);   // (8, 64) = 512 blocks = 2/CU
    dim3 block(512);                           // 4 row-groups x 2 k-halves
    hipLaunchKernelGGL(morph_kernel, grid, block, 0, stream, x, wd, we, out);
}